// Round 3
// baseline (73.786 us; speedup 1.0000x reference)
//
#include <hip/hip_runtime.h>
#include <hip/hip_bf16.h>
#include <stdint.h>

#define MB_ 16384
#define NN_ 1024
#define KK_ 1024

typedef __bf16 bhalf;
typedef __bf16 bhalf8 __attribute__((ext_vector_type(8)));
typedef __bf16 bhalf4 __attribute__((ext_vector_type(4)));
typedef float f32x4 __attribute__((ext_vector_type(4)));

typedef const __attribute__((address_space(1))) void* gas_ptr;
typedef __attribute__((address_space(3))) void* las_ptr;

__device__ __forceinline__ void gload_lds16(const void* g, void* l) {
  __builtin_amdgcn_global_load_lds((gas_ptr)g, (las_ptr)l, 16, 0, 0);
}

// ---------------- K1a: partial column max / sumexp ----------------
__global__ void k_colpart(const float* __restrict__ W,
                          float* __restrict__ pM, float* __restrict__ pS) {
  int col = blockIdx.x * 256 + threadIdx.x;
  int rc  = blockIdx.y;
  const float* p = W + (size_t)rc * 32 * NN_ + col;
  float v[32];
#pragma unroll
  for (int i = 0; i < 32; ++i) v[i] = p[(size_t)i * NN_];
  float m = v[0];
#pragma unroll
  for (int i = 1; i < 32; ++i) m = fmaxf(m, v[i]);
  float s = 0.f;
#pragma unroll
  for (int i = 0; i < 32; ++i) s += __expf(v[i] - m);
  pM[rc * NN_ + col] = m;
  pS[rc * NN_ + col] = s;
}

// ---------------- K1b: combine partials -> colLSE ----------------
__global__ void k_colfin(const float* __restrict__ pM, const float* __restrict__ pS,
                         float* __restrict__ colLSE) {
  int col = blockIdx.x * 256 + threadIdx.x;
  float m = -1e30f;
#pragma unroll
  for (int i = 0; i < 32; ++i) m = fmaxf(m, pM[i * NN_ + col]);
  float s = 0.f;
#pragma unroll
  for (int i = 0; i < 32; ++i) s += pS[i * NN_ + col] * __expf(pM[i * NN_ + col] - m);
  colLSE[col] = m + __logf(s);
}

// ---------------- K2: expA[i,k] = exp(W[i,k]-colLSE[k]-mA[i]), mA[i] ----------------
__global__ void k_expA(const float* __restrict__ W, const float* __restrict__ colLSE,
                       bhalf* __restrict__ eA, float* __restrict__ mA) {
  int i = blockIdx.x;
  int l = threadIdx.x;
  const float4* row = (const float4*)(W + (size_t)i * NN_);
  const float4* cls = (const float4*)colLSE;
  float4 v[4];
#pragma unroll
  for (int t = 0; t < 4; ++t) {
    float4 wv = row[t * 64 + l];
    float4 cv = cls[t * 64 + l];
    v[t].x = wv.x - cv.x; v[t].y = wv.y - cv.y;
    v[t].z = wv.z - cv.z; v[t].w = wv.w - cv.w;
  }
  float m = -1e30f;
#pragma unroll
  for (int t = 0; t < 4; ++t)
    m = fmaxf(m, fmaxf(fmaxf(v[t].x, v[t].y), fmaxf(v[t].z, v[t].w)));
#pragma unroll
  for (int off = 32; off; off >>= 1) m = fmaxf(m, __shfl_xor(m, off));
#pragma unroll
  for (int t = 0; t < 4; ++t) {
    bhalf4 o;
    o[0] = (bhalf)__expf(v[t].x - m);
    o[1] = (bhalf)__expf(v[t].y - m);
    o[2] = (bhalf)__expf(v[t].z - m);
    o[3] = (bhalf)__expf(v[t].w - m);
    *(bhalf4*)(eA + (size_t)i * NN_ + t * 256 + l * 4) = o;
  }
  if (l == 0) mA[i] = m;
}

// ---------------- K3: expB[b,k] = exp(la[b,k]-mB[b]), mB[b] ----------------
__global__ void k_expB(const float* __restrict__ LA,
                       bhalf* __restrict__ eB, float* __restrict__ mB) {
  int b = blockIdx.x;
  int l = threadIdx.x;
  const float4* row = (const float4*)(LA + (size_t)b * NN_);
  float4 v[4];
#pragma unroll
  for (int t = 0; t < 4; ++t) v[t] = row[t * 64 + l];
  float m = -1e30f;
#pragma unroll
  for (int t = 0; t < 4; ++t)
    m = fmaxf(m, fmaxf(fmaxf(v[t].x, v[t].y), fmaxf(v[t].z, v[t].w)));
#pragma unroll
  for (int off = 32; off; off >>= 1) m = fmaxf(m, __shfl_xor(m, off));
#pragma unroll
  for (int t = 0; t < 4; ++t) {
    bhalf4 o;
    o[0] = (bhalf)__expf(v[t].x - m);
    o[1] = (bhalf)__expf(v[t].y - m);
    o[2] = (bhalf)__expf(v[t].z - m);
    o[3] = (bhalf)__expf(v[t].w - m);
    *(bhalf4*)(eB + (size_t)b * NN_ + t * 256 + l * 4) = o;
  }
  if (l == 0) mB[b] = m;
}

// ---------------- GEMM: 256x256 tile, BK=64, 512 thr (8 waves 2Mx4N) ----------------
// out[b,i] = log(sum_k eB[b,k]*eA[i,k]) + mB[b] + mA[i]
// LDS: A dbuf [0,64K), B dbuf [64K,128K). Buf stride 32K, half stride 16K.
// 2-tile unrolled body: all LDS read addrs = loop-invariant base + const offset.
// Stage schedule per tile t (buf=t&1): q0 A(t+1)h0, q1 A(t+1)h1, q2 B(t+2)h0,
// q3 B(t+2)h1 then vmcnt(4) (leaves B(t+2) in flight across the barrier).

#define VM4   asm volatile("s_waitcnt vmcnt(4)" ::: "memory")
#define VM0   asm volatile("s_waitcnt vmcnt(0)" ::: "memory")
#define HINT8 asm volatile("s_waitcnt lgkmcnt(8)" ::: "memory")
#define NOPS  ((void)0)

#define STA(BUF, H, TOFF) do {                                            \
    const bhalf* g_ = pgA + (H) * 131072 + (TOFF) * 64;                   \
    unsigned char* d_ = lds + (BUF) * 32768 + (H) * 16384 + tid * 16;     \
    gload_lds16(g_, d_); gload_lds16(g_ + 65536, d_ + 8192); } while (0)

#define STB(BUF, H, TOFF) do {                                            \
    const bhalf* g_ = pgB + (H) * 131072 + (TOFF) * 64;                   \
    unsigned char* d_ = lds + 65536 + (BUF) * 32768 + (H) * 16384 + tid * 16; \
    gload_lds16(g_, d_); gload_lds16(g_ + 65536, d_ + 8192); } while (0)

#define MFMA8(Q)                                                          \
  __builtin_amdgcn_s_setprio(1);                                          \
  _Pragma("unroll")                                                       \
  for (int m_ = 0; m_ < 2; ++m_)                                          \
    _Pragma("unroll")                                                     \
    for (int n_ = 0; n_ < 4; ++n_)                                        \
      _Pragma("unroll")                                                   \
      for (int kk_ = 0; kk_ < 2; ++kk_)                                   \
        acc[2 * (Q) + m_][n_] = __builtin_amdgcn_mfma_f32_16x16x32_bf16(  \
            af[m_][kk_], bq[n_][kk_], acc[2 * (Q) + m_][n_], 0, 0, 0);    \
  __builtin_amdgcn_s_setprio(0);

#define PHASE(BUF, Q, STG, PRE)                                           \
  af[0][0] = *(const bhalf8*)(pA0 + (BUF) * 32768 + (Q) * 4096);          \
  af[0][1] = *(const bhalf8*)(pA1 + (BUF) * 32768 + (Q) * 4096);          \
  af[1][0] = *(const bhalf8*)(pA0 + (BUF) * 32768 + (Q) * 4096 + 2048);   \
  af[1][1] = *(const bhalf8*)(pA1 + (BUF) * 32768 + (Q) * 4096 + 2048);   \
  if ((Q) == 0) {                                                         \
    _Pragma("unroll")                                                     \
    for (int n_ = 0; n_ < 4; ++n_) {                                      \
      bq[n_][0] = *(const bhalf8*)(pB0 + (BUF) * 32768 + n_ * 2048);      \
      bq[n_][1] = *(const bhalf8*)(pB1 + (BUF) * 32768 + n_ * 2048);      \
    }                                                                     \
  }                                                                       \
  STG;                                                                    \
  PRE;                                                                    \
  __builtin_amdgcn_sched_barrier(0);                                      \
  __builtin_amdgcn_s_barrier();                                           \
  asm volatile("s_waitcnt lgkmcnt(0)" ::: "memory");                      \
  __builtin_amdgcn_sched_barrier(0);                                      \
  MFMA8(Q);                                                               \
  __builtin_amdgcn_s_barrier();

#define KTILE(BUF, S0, S1, S2, S3, PRE0, PRE3)                            \
  {                                                                       \
    bhalf8 bq[4][2];                                                      \
    bhalf8 af[2][2];                                                      \
    PHASE(BUF, 0, S0, PRE0)                                               \
    PHASE(BUF, 1, S1, NOPS)                                               \
    PHASE(BUF, 2, S2, NOPS)                                               \
    PHASE(BUF, 3, S3, PRE3)                                               \
  }

__global__ __launch_bounds__(512, 2) void k_gemm(const bhalf* __restrict__ A,  // eB [M][K]
                                                 const bhalf* __restrict__ Bt, // eA [N][K]
                                                 const float* __restrict__ mB,
                                                 const float* __restrict__ mA,
                                                 float* __restrict__ out) {
  __shared__ __align__(16) unsigned char lds[131072];

  const int nwg = gridDim.x;              // 256, %8==0
  const int wg  = blockIdx.x;
  const int swz = (wg & 7) * (nwg >> 3) + (wg >> 3);
  const int bm = swz >> 2;                // 0..63
  const int bn = swz & 3;                 // 0..3

  const int tid = threadIdx.x;
  const int l = tid & 63;
  const int w = tid >> 6;
  const int wr = w >> 2;                  // 0..1 (M)
  const int wc = w & 3;                   // 0..3 (N)

  // staging geometry: thread covers rows r8, r8+64 of each 128-row half, chunk tid&7
  const int r8  = tid >> 3;               // 0..63
  const int kel = (((tid & 7) ^ (r8 & 7)) << 3);   // pre-swizzled source element offset
  const bhalf* pgA = A  + (size_t)(bm * 256 + r8) * KK_ + kel;
  const bhalf* pgB = Bt + (size_t)(bn * 256 + r8) * KK_ + kel;

  // loop-invariant LDS read bases (row%8 == l%8 for every fragment row)
  const int kx  = 16 * (l >> 4);
  const int x16 = (l & 7) << 4;
  const int kx0 = kx ^ x16;
  const int kx1 = (64 + kx) ^ x16;
  const unsigned char* pA0 = lds + wr * 16384 + (l & 15) * 128 + kx0;
  const unsigned char* pA1 = lds + wr * 16384 + (l & 15) * 128 + kx1;
  const unsigned char* pB0 = lds + 65536 + (wc >> 1) * 16384 + ((wc & 1) * 64 + (l & 15)) * 128 + kx0;
  const unsigned char* pB1 = lds + 65536 + (wc >> 1) * 16384 + ((wc & 1) * 64 + (l & 15)) * 128 + kx1;

  f32x4 zero = {0.f, 0.f, 0.f, 0.f};
  f32x4 acc[8][4];
#pragma unroll
  for (int m = 0; m < 8; ++m)
#pragma unroll
    for (int n = 0; n < 4; ++n) acc[m][n] = zero;

  // prologue: K-tile 0 (A+B) and B of K-tile 1; vmcnt(4) -> A0,B0 landed.
  STA(0, 0, 0); STA(0, 1, 0);
  STB(0, 0, 0); STB(0, 1, 0);
  STB(1, 0, 1); STB(1, 1, 1);
  VM4;
  __builtin_amdgcn_s_barrier();

  // 16 K-tiles: 7 unrolled pairs + peeled tail pair (tiles 14,15)
  for (int p = 0; p < 7; ++p) {
    KTILE(0, STA(1, 0, 1), STA(1, 1, 1), STB(0, 0, 2), STB(0, 1, 2), HINT8, VM4)
    KTILE(1, STA(0, 0, 2), STA(0, 1, 2), STB(1, 0, 3), STB(1, 1, 3), HINT8, VM4)
    pgA += 128;
    pgB += 128;
  }
  KTILE(0, STA(1, 0, 1), STA(1, 1, 1), NOPS, NOPS, HINT8, VM0)
  KTILE(1, NOPS, NOPS, NOPS, NOPS, HINT8, NOPS)

  // epilogue: D row = 4*(l>>4)+r (+16 per m-frag), col = l&15 (+16 per n-frag)
  const int c0 = bn * 256 + wc * 64 + (l & 15);
  const int r0 = bm * 256 + wr * 128 + (l >> 4) * 4;
  float mav[4];
#pragma unroll
  for (int nf = 0; nf < 4; ++nf) mav[nf] = mA[c0 + nf * 16];
#pragma unroll
  for (int mf = 0; mf < 8; ++mf) {
#pragma unroll
    for (int r = 0; r < 4; ++r) {
      const int row = r0 + mf * 16 + r;
      const float mb = mB[row];
      float* o = out + (size_t)row * NN_ + c0;
#pragma unroll
      for (int nf = 0; nf < 4; ++nf)
        __builtin_nontemporal_store(__logf(acc[mf][nf][r]) + mb + mav[nf], o + nf * 16);
    }
  }
}

extern "C" void kernel_launch(void* const* d_in, const int* in_sizes, int n_in,
                              void* d_out, int out_size, void* d_ws, size_t ws_size,
                              hipStream_t stream) {
  const float* log_alpha = (const float*)d_in[0];  // [16384,1024] f32
  const float* W         = (const float*)d_in[1];  // [1024,1024] f32
  float* out = (float*)d_out;                      // [16384,1024] f32

  uintptr_t ws = (uintptr_t)d_ws;
  bhalf* eB     = (bhalf*)(ws);                    // 33,554,432 B
  bhalf* eA     = (bhalf*)(ws + 33554432);         //  2,097,152 B
  float* mB     = (float*)(ws + 35651584);         //     65,536 B
  float* mA     = (float*)(ws + 35717120);         //      4,096 B
  float* colLSE = (float*)(ws + 35721216);         //      4,096 B
  float* pM     = (float*)(ws + 35725312);         //    131,072 B
  float* pS     = (float*)(ws + 35856384);         //    131,072 B

  k_colpart<<<dim3(4, 32), 256, 0, stream>>>(W, pM, pS);
  k_colfin<<<4, 256, 0, stream>>>(pM, pS, colLSE);
  k_expA<<<NN_, 64, 0, stream>>>(W, colLSE, eA, mA);
  k_expB<<<MB_, 64, 0, stream>>>(log_alpha, eB, mB);
  k_gemm<<<(MB_ / 256) * (NN_ / 256), 512, 0, stream>>>(eB, eA, mB, mA, out);
}